// Round 4
// baseline (129.050 us; speedup 1.0000x reference)
//
#include <hip/hip_runtime.h>

typedef __attribute__((ext_vector_type(8))) __bf16 bf16x8;
typedef __attribute__((ext_vector_type(4))) float floatx4;
typedef __attribute__((ext_vector_type(16))) float floatx16;

__device__ __forceinline__ unsigned short f2bf(float f) {
    unsigned int u = __builtin_bit_cast(unsigned int, f);
    unsigned int r = u + 0x7FFFu + ((u >> 16) & 1u);
    return (unsigned short)(r >> 16);
}

// Prep: fp32 weight [512][64] -> bf16 table + per-row squared norms.
__global__ void vq_prep(const float* __restrict__ w, unsigned short* __restrict__ wbf,
                        float* __restrict__ wsq) {
    const int t = threadIdx.x;
    const int row = blockIdx.x * 4 + (t >> 6);
    const int c = t & 63;
    float v = w[row * 64 + c];
    wbf[row * 64 + c] = f2bf(v);
    float s = v * v;
#pragma unroll
    for (int off = 32; off; off >>= 1) s += __shfl_xor(s, off, 64);
    if (c == 0) wsq[row] = s;
}

// One wave per 32-position tile; wave scans all 512 codes via 32x32x16 MFMA.
// Zero cross-wave coupling; argmin via mantissa-packed score; loss from scores.
__global__ void __launch_bounds__(64, 4) vq_main(
    const float* __restrict__ in,            // [32][64][4096] NCHW (HW flattened)
    const float* __restrict__ w,             // [512][64] fp32
    const unsigned short* __restrict__ wbf,  // [512][64] bf16
    const float* __restrict__ wsq,           // [512]
    float* __restrict__ out,                 // [32][64][4096]
    float* __restrict__ partials) {          // [4096] per-wave loss sums
    __shared__ unsigned short xs[8 * 32 * 8];  // [g=k>>3][pos][e=k&7] bf16

    const int lane = threadIdx.x;
    const int bid = blockIdx.x;
    const int b = bid >> 7;                 // batch
    const int s0 = (bid & 127) << 5;        // spatial tile start (32 positions)

    const float* in_base = in + ((size_t)b * 64) * 4096 + s0;
    const int c0 = lane >> 3;               // 0..7
    const int jj = (lane & 7) * 4;          // 0..28

    // stage X tile (bf16) + fp32 ||x||^2 partial
    float x2 = 0.f;
#pragma unroll
    for (int co = 0; co < 64; co += 8) {
        const int k = co + c0;
        floatx4 v = *(const floatx4*)(in_base + (size_t)k * 4096 + jj);
        x2 += v[0] * v[0] + v[1] * v[1] + v[2] * v[2] + v[3] * v[3];
        const int g = k >> 3, e = k & 7;
        unsigned short* p = &xs[(g * 32 + jj) * 8 + e];
        p[0]  = f2bf(v[0]);
        p[8]  = f2bf(v[1]);
        p[16] = f2bf(v[2]);
        p[24] = f2bf(v[3]);
    }
    __syncthreads();  // single wave: near-free

    const int hi = lane >> 5;   // k-half select
    const int col = lane & 31;  // position (B col / C col)

    // B fragments: pos=col, k = ch*16 + hi*8 + e  (contiguous ds_read_b128)
    bf16x8 Bf[4];
#pragma unroll
    for (int ch = 0; ch < 4; ++ch) {
        const int g = 2 * ch + hi;
        Bf[ch] = *(const bf16x8*)&xs[(g * 32 + col) * 8];
    }

    float best = 1e30f;
#pragma unroll 2
    for (int ct = 0; ct < 16; ++ct) {
        const int code_base = ct * 32;
        // A: code row = code_base+col, k = ch*16 + hi*8 + e
        const unsigned short* arow = wbf + (code_base + col) * 64 + hi * 8;
        bf16x8 A0 = *(const bf16x8*)(arow);
        bf16x8 A1 = *(const bf16x8*)(arow + 16);
        bf16x8 A2 = *(const bf16x8*)(arow + 32);
        bf16x8 A3 = *(const bf16x8*)(arow + 48);
        floatx16 acc = {0.f, 0.f, 0.f, 0.f, 0.f, 0.f, 0.f, 0.f,
                        0.f, 0.f, 0.f, 0.f, 0.f, 0.f, 0.f, 0.f};
        acc = __builtin_amdgcn_mfma_f32_32x32x16_bf16(A0, Bf[0], acc, 0, 0, 0);
        acc = __builtin_amdgcn_mfma_f32_32x32x16_bf16(A1, Bf[1], acc, 0, 0, 0);
        acc = __builtin_amdgcn_mfma_f32_32x32x16_bf16(A2, Bf[2], acc, 0, 0, 0);
        acc = __builtin_amdgcn_mfma_f32_32x32x16_bf16(A3, Bf[3], acc, 0, 0, 0);
        // score = ||w||^2 - 2 x.w ; C/D row = (r&3) + 8*(r>>2) + 4*hi
#pragma unroll
        for (int q = 0; q < 4; ++q) {
            floatx4 wq = *(const floatx4*)&wsq[code_base + 8 * q + 4 * hi];
#pragma unroll
            for (int rr = 0; rr < 4; ++rr) {
                const int r = q * 4 + rr;
                const float sc = __builtin_fmaf(-2.f, acc[r], wq[rr]);
                const unsigned int code = (unsigned int)(code_base + 8 * q + 4 * hi + rr);
                const unsigned int ub =
                    (__builtin_bit_cast(unsigned int, sc) & 0xFFFFFE00u) | code;
                best = fminf(best, __builtin_bit_cast(float, ub));
            }
        }
    }
    // combine the two k-half row sets: lanes l and l+32 share col
    best = fminf(best, __shfl_xor(best, 32, 64));

    // loss partial: sum of min-scores over the 32 positions + sum x^2
    const float smin =
        __builtin_bit_cast(float, __builtin_bit_cast(unsigned int, best) & 0xFFFFFE00u);
    float tot = x2 + (lane < 32 ? smin : 0.f);
#pragma unroll
    for (int off = 1; off < 64; off <<= 1) tot += __shfl_xor(tot, off, 64);
    if (lane == 0) partials[bid] = tot;

    // epilogue: gather fp32 code rows, write out (coalesced float4)
    int idxr[4];
#pragma unroll
    for (int r = 0; r < 4; ++r) {
        const float pk = __shfl(best, jj + r, 64);
        idxr[r] = (int)(__builtin_bit_cast(unsigned int, pk) & 511u);
    }
    float* out_base = out + ((size_t)b * 64) * 4096 + s0;
#pragma unroll
    for (int co = 0; co < 64; co += 8) {
        const int c = co + c0;
        floatx4 qv;
#pragma unroll
        for (int r = 0; r < 4; ++r) qv[r] = w[idxr[r] * 64 + c];
        *(floatx4*)(out_base + (size_t)c * 4096 + jj) = qv;
    }
}

// Final: sum 4096 per-wave partials -> scalar loss (no atomics anywhere).
__global__ void vq_reduce(const float* __restrict__ partials, float* __restrict__ loss) {
    const int t = threadIdx.x;
    float s = 0.f;
#pragma unroll
    for (int i = 0; i < 16; ++i) s += partials[t + i * 256];
#pragma unroll
    for (int off = 32; off; off >>= 1) s += __shfl_xor(s, off, 64);
    __shared__ float ws4[4];
    if ((t & 63) == 0) ws4[t >> 6] = s;
    __syncthreads();
    if (t == 0) loss[0] = (ws4[0] + ws4[1] + ws4[2] + ws4[3]) * (1.25f / 8388608.f);
}

extern "C" void kernel_launch(void* const* d_in, const int* in_sizes, int n_in,
                              void* d_out, int out_size, void* d_ws, size_t ws_size,
                              hipStream_t stream) {
    const float* in = (const float*)d_in[0];
    const float* w  = (const float*)d_in[1];
    float* out = (float*)d_out;
    float* loss = out + 8388608;  // second output (scalar), concatenated
    unsigned short* wbf = (unsigned short*)d_ws;                   // 64 KB bf16 codebook
    float* wsq = (float*)((char*)d_ws + 512 * 64 * 2);             // 2 KB norms
    float* partials = (float*)((char*)d_ws + 512 * 64 * 2 + 2048); // 16 KB per-wave sums

    vq_prep<<<128, 256, 0, stream>>>(w, wbf, wsq);
    vq_main<<<4096, 64, 0, stream>>>(in, w, wbf, wsq, out, partials);
    vq_reduce<<<1, 256, 0, stream>>>(partials, loss);
}

// Round 5
// 101.224 us; speedup vs baseline: 1.2749x; 1.2749x over previous
//
#include <hip/hip_runtime.h>

typedef __attribute__((ext_vector_type(8))) __bf16 bf16x8;
typedef __attribute__((ext_vector_type(4))) float floatx4;
typedef __attribute__((ext_vector_type(16))) float floatx16;

__device__ __forceinline__ unsigned short f2bf(float f) {
    unsigned int u = __builtin_bit_cast(unsigned int, f);
    unsigned int r = u + 0x7FFFu + ((u >> 16) & 1u);
    return (unsigned short)(r >> 16);
}

// Prep: fp32 weight [512][64] -> bf16 table + per-row squared norms.
__global__ void vq_prep(const float* __restrict__ w, unsigned short* __restrict__ wbf,
                        float* __restrict__ wsq) {
    const int t = threadIdx.x;
    const int row = blockIdx.x * 4 + (t >> 6);
    const int c = t & 63;
    float v = w[row * 64 + c];
    wbf[row * 64 + c] = f2bf(v);
    float s = v * v;
#pragma unroll
    for (int off = 32; off; off >>= 1) s += __shfl_xor(s, off, 64);
    if (c == 0) wsq[row] = s;
}

// 256 blocks (1/CU) x 512 threads (8 waves). Codebook staged ONCE into LDS
// (XOR-swizzled). Each wave: 2 sequential 32-position tiles, input for tile 2
// register-prefetched under tile-1 compute. Waves independent after staging.
__global__ void __launch_bounds__(512, 2) vq_main(
    const float* __restrict__ in,            // [32][64][4096]
    const float* __restrict__ w,             // [512][64] fp32
    const unsigned short* __restrict__ wbf,  // [512][64] bf16
    const float* __restrict__ wsq,           // [512]
    float* __restrict__ out,                 // [32][64][4096]
    float* __restrict__ partials) {          // [2048] per-wave loss sums
    __shared__ unsigned short cb[32768];     // 64 KB swizzled bf16 codebook
    __shared__ float wsqs[512];
    __shared__ unsigned short xw[8][2048];   // per-wave X tile [g][pos][e]

    const int t = threadIdx.x;
    const int lane = t & 63;
    const int wv = t >> 6;
    const int bid = blockIdx.x;
    const int c0 = lane >> 3;               // 0..7
    const int jj = (lane & 7) * 4;          // 0..28

    // ---- stage codebook (swizzled) + wsq; issue tile-1 input loads ----
    bf16x8 cbv[8];
#pragma unroll
    for (int i = 0; i < 8; ++i)
        cbv[i] = *(const bf16x8*)((const char*)wbf + t * 16 + i * 8192);
    const float wq1 = wsq[t];

    const int gt1 = bid * 16 + wv;               // tile for round 1
    const float* in1 = in + ((size_t)(gt1 >> 7) * 64) * 4096 + ((gt1 & 127) << 5);
    floatx4 xr[8];
#pragma unroll
    for (int i = 0; i < 8; ++i)
        xr[i] = *(const floatx4*)(in1 + (size_t)(i * 8 + c0) * 4096 + jj);

#pragma unroll
    for (int i = 0; i < 8; ++i) {
        const unsigned int o = (unsigned int)(t * 16 + i * 8192);
        const unsigned int dst = o ^ (((o >> 7) & 7u) << 4);
        *(bf16x8*)((char*)cb + dst) = cbv[i];
    }
    wsqs[t] = wq1;
    __syncthreads();

    // ---- write X1 to own LDS buffer, compute ||x||^2 ----
    float x2a = 0.f;
#pragma unroll
    for (int i = 0; i < 8; ++i) {
        floatx4 v = xr[i];
        x2a += v[0] * v[0] + v[1] * v[1] + v[2] * v[2] + v[3] * v[3];
        unsigned short* p = &xw[wv][(i * 32 + jj) * 8 + c0];
        p[0] = f2bf(v[0]); p[8] = f2bf(v[1]); p[16] = f2bf(v[2]); p[24] = f2bf(v[3]);
    }
    __syncthreads();

    // ---- prefetch tile-2 input into registers (overlaps tile-1 compute) ----
    const int gt2 = bid * 16 + 8 + wv;
    const float* in2 = in + ((size_t)(gt2 >> 7) * 64) * 4096 + ((gt2 & 127) << 5);
#pragma unroll
    for (int i = 0; i < 8; ++i)
        xr[i] = *(const floatx4*)(in2 + (size_t)(i * 8 + c0) * 4096 + jj);

    const int hi = lane >> 5;
    const int col = lane & 31;
    // per-lane swizzled cb byte addresses for the 4 k-chunks
    unsigned int cba[4];
#pragma unroll
    for (int ch = 0; ch < 4; ++ch) {
        const unsigned int raw = (unsigned int)(col * 128 + ch * 32 + hi * 16);
        cba[ch] = raw ^ (((unsigned int)(col & 7)) << 4);
    }

    float tot_all = 0.f;
#pragma unroll
    for (int round = 0; round < 2; ++round) {
        const int gt = round ? gt2 : gt1;
        const float x2 = round ? 0.f : x2a;  // round-2 x2 computed at its write
        float x2r = x2;

        if (round) {
            // write X2 (own buffer; wave finished reading X1)
            float s2 = 0.f;
#pragma unroll
            for (int i = 0; i < 8; ++i) {
                floatx4 v = xr[i];
                s2 += v[0] * v[0] + v[1] * v[1] + v[2] * v[2] + v[3] * v[3];
                unsigned short* p = &xw[wv][(i * 32 + jj) * 8 + c0];
                p[0] = f2bf(v[0]); p[8] = f2bf(v[1]); p[16] = f2bf(v[2]); p[24] = f2bf(v[3]);
            }
            x2r = s2;
            __syncthreads();   // order X2 writes before B reads (uniform)
        }

        // B fragments from own X buffer
        bf16x8 Bf[4];
#pragma unroll
        for (int ch = 0; ch < 4; ++ch)
            Bf[ch] = *(const bf16x8*)&xw[wv][((2 * ch + hi) * 32 + col) * 8];

        float best = 1e30f;
#pragma unroll 2
        for (int ct = 0; ct < 16; ++ct) {
            const char* cbase = (const char*)cb + ct * 4096;
            bf16x8 A0 = *(const bf16x8*)(cbase + cba[0]);
            bf16x8 A1 = *(const bf16x8*)(cbase + cba[1]);
            bf16x8 A2 = *(const bf16x8*)(cbase + cba[2]);
            bf16x8 A3 = *(const bf16x8*)(cbase + cba[3]);
            floatx16 acc = {0.f, 0.f, 0.f, 0.f, 0.f, 0.f, 0.f, 0.f,
                            0.f, 0.f, 0.f, 0.f, 0.f, 0.f, 0.f, 0.f};
            acc = __builtin_amdgcn_mfma_f32_32x32x16_bf16(A0, Bf[0], acc, 0, 0, 0);
            acc = __builtin_amdgcn_mfma_f32_32x32x16_bf16(A1, Bf[1], acc, 0, 0, 0);
            acc = __builtin_amdgcn_mfma_f32_32x32x16_bf16(A2, Bf[2], acc, 0, 0, 0);
            acc = __builtin_amdgcn_mfma_f32_32x32x16_bf16(A3, Bf[3], acc, 0, 0, 0);
            const int code_base = ct * 32;
#pragma unroll
            for (int q = 0; q < 4; ++q) {
                floatx4 wq = *(const floatx4*)&wsqs[code_base + 8 * q + 4 * hi];
#pragma unroll
                for (int rr = 0; rr < 4; ++rr) {
                    const int r = q * 4 + rr;
                    const float sc = __builtin_fmaf(-2.f, acc[r], wq[rr]);
                    const unsigned int code = (unsigned int)(code_base + 8 * q + 4 * hi + rr);
                    const unsigned int ub =
                        (__builtin_bit_cast(unsigned int, sc) & 0xFFFFFE00u) | code;
                    best = fminf(best, __builtin_bit_cast(float, ub));
                }
            }
        }
        best = fminf(best, __shfl_xor(best, 32, 64));

        const float smin =
            __builtin_bit_cast(float, __builtin_bit_cast(unsigned int, best) & 0xFFFFFE00u);
        float tot = x2r + (lane < 32 ? smin : 0.f);
#pragma unroll
        for (int off = 1; off < 64; off <<= 1) tot += __shfl_xor(tot, off, 64);
        tot_all += tot;

        // epilogue: gather fp32 code rows from global, write out
        int idxr[4];
#pragma unroll
        for (int r = 0; r < 4; ++r) {
            const float pk = __shfl(best, jj + r, 64);
            idxr[r] = (int)(__builtin_bit_cast(unsigned int, pk) & 511u);
        }
        float* out_base = out + ((size_t)(gt >> 7) * 64) * 4096 + ((gt & 127) << 5);
#pragma unroll
        for (int co = 0; co < 64; co += 8) {
            const int c = co + c0;
            floatx4 qv;
#pragma unroll
            for (int r = 0; r < 4; ++r) qv[r] = w[idxr[r] * 64 + c];
            *(floatx4*)(out_base + (size_t)c * 4096 + jj) = qv;
        }
    }

    if (lane == 0) partials[bid * 8 + wv] = tot_all;
}

// Final: sum 2048 per-wave partials -> scalar loss.
__global__ void vq_reduce(const float* __restrict__ partials, float* __restrict__ loss) {
    const int t = threadIdx.x;
    float s = 0.f;
#pragma unroll
    for (int i = 0; i < 8; ++i) s += partials[t + i * 256];
#pragma unroll
    for (int off = 32; off; off >>= 1) s += __shfl_xor(s, off, 64);
    __shared__ float ws4[4];
    if ((t & 63) == 0) ws4[t >> 6] = s;
    __syncthreads();
    if (t == 0) loss[0] = (ws4[0] + ws4[1] + ws4[2] + ws4[3]) * (1.25f / 8388608.f);
}

extern "C" void kernel_launch(void* const* d_in, const int* in_sizes, int n_in,
                              void* d_out, int out_size, void* d_ws, size_t ws_size,
                              hipStream_t stream) {
    const float* in = (const float*)d_in[0];
    const float* w  = (const float*)d_in[1];
    float* out = (float*)d_out;
    float* loss = out + 8388608;  // second output (scalar), concatenated
    unsigned short* wbf = (unsigned short*)d_ws;                   // 64 KB bf16 codebook
    float* wsq = (float*)((char*)d_ws + 512 * 64 * 2);             // 2 KB norms
    float* partials = (float*)((char*)d_ws + 512 * 64 * 2 + 2048); // 8 KB per-wave sums

    vq_prep<<<128, 256, 0, stream>>>(w, wbf, wsq);
    vq_main<<<256, 512, 0, stream>>>(in, w, wbf, wsq, out, partials);
    vq_reduce<<<1, 256, 0, stream>>>(partials, loss);
}